// Round 8
// baseline (376.696 us; speedup 1.0000x reference)
//
#include <hip/hip_runtime.h>
#include <math.h>

typedef unsigned int  u32;
typedef unsigned short u16;

// Problem constants (match reference)
#define NN    50000
#define NE    800000
#define ET    (NE + NN)     // edges + self loops = 850000
#define IND   128
#define HIDD  128
#define NH    8
#define OD    64
#define SLOPE 0.2f

// Binned counting sort parameters
#define NB    196           // buckets of 256 nodes: ceil(50000/256)
#define NPART 8             // XCD-aligned sub-buckets (blockIdx & 7)
#define CAPX  1024          // capacity per (part,bucket): mean 544, +20 sigma

// bf16 round-to-nearest-even, returns low 16 bits
__device__ __forceinline__ u32 bf16rne(float f) {
    u32 u = __float_as_uint(f);
    return (u + 0x7fffu + ((u >> 16) & 1u)) >> 16;
}

// leaky_relu(s) == max(s, SLOPE*s) for 0 < SLOPE < 1
#define LR(s) fmaxf((s), SLOPE * (s))

// ---------------------------------------------------------------------------
// Phase 1: bin edges by (part, dst>>8). Sequential writes per sub-bucket
// frontier (atomic cursor) -> ~no write amplification; part = blockIdx&7
// aligns each frontier with one XCD's L2.
// ---------------------------------------------------------------------------
__global__ __launch_bounds__(256) void k_bin(
    const int* __restrict__ ei, int* __restrict__ cnt, u32* __restrict__ staging)
{
    const int e = blockIdx.x * 256 + threadIdx.x;
    if (e >= ET) return;
    int src, dst;
    if (e < NE) { src = ei[e]; dst = ei[NE + e]; }
    else        { src = dst = e - NE; }
    const int slot = (blockIdx.x & (NPART - 1)) * NB + (dst >> 8);
    const int pos = atomicAdd(&cnt[slot], 1);
    staging[slot * CAPX + pos] = ((u32)(dst & 255) << 16) | (u32)src;
}

// ---------------------------------------------------------------------------
// Phase 2: one block per bucket (256 consecutive nodes = contiguous CSR
// region). LDS histogram -> scan -> emits rowptr/rowend (replaces deg+scan
// kernels) -> places u16 src via LDS cursors. All random writes land in an
// ~9 KB region owned by this block's CU.
// ---------------------------------------------------------------------------
__global__ __launch_bounds__(1024) void k_place(
    const int* __restrict__ cnt, const u32* __restrict__ staging,
    int* __restrict__ rowptr, int* __restrict__ rowend,
    u16* __restrict__ sorted16)
{
    __shared__ int tot[NB];
    __shared__ int scnt[NPART];
    __shared__ int hist[256];
    __shared__ int cur[256];
    __shared__ int scan[256];
    __shared__ int cbase;
    const int b = blockIdx.x;
    const int t = threadIdx.x;

    if (t < NB) {
        int s = 0;
        for (int p = 0; p < NPART; ++p) s += cnt[p * NB + t];
        tot[t] = s;
    }
    if (t < NPART) scnt[t] = cnt[t * NB + b];
    if (t < 256) hist[t] = 0;
    __syncthreads();
    if (t == 0) {                        // CSR base of this bucket
        int run = 0;
        for (int i = 0; i < b; ++i) run += tot[i];
        cbase = run;
    }
    __syncthreads();
    const int base = cbase;

    // pass 1: per-node histogram
    for (int idx = t; idx < NPART * CAPX; idx += 1024) {
        const int p = idx >> 10;         // CAPX == 1024
        const int i = idx & (CAPX - 1);
        if (i < scnt[p]) {
            const u32 v = staging[(p * NB + b) * CAPX + i];
            atomicAdd(&hist[v >> 16], 1);
        }
    }
    __syncthreads();
    // inclusive scan (Hillis-Steele) over 256
    if (t < 256) scan[t] = hist[t];
    __syncthreads();
    for (int off = 1; off < 256; off <<= 1) {
        int v = 0;
        if (t < 256 && t >= off) v = scan[t - off];
        __syncthreads();
        if (t < 256) scan[t] += v;
        __syncthreads();
    }
    if (t < 256) {
        const int excl = (t == 0) ? 0 : scan[t - 1];
        cur[t] = excl;
        const int node = b * 256 + t;
        if (node < NN) {
            rowptr[node] = base + excl;
            rowend[node] = base + excl + hist[t];
        }
    }
    __syncthreads();
    // pass 2: place (staged data is L2-hot from pass 1)
    for (int idx = t; idx < NPART * CAPX; idx += 1024) {
        const int p = idx >> 10;
        const int i = idx & (CAPX - 1);
        if (i < scnt[p]) {
            const u32 v = staging[(p * NB + b) * CAPX + i];
            const int pos = atomicAdd(&cur[v >> 16], 1);
            sorted16[base + pos] = (u16)(v & 0xffffu);
        }
    }
}

// ---------------------------------------------------------------------------
// Register-tiled fp32 GEMMs (64x64 C tile, K=128 staged, XOR-swizzled x tile).
// ---------------------------------------------------------------------------
#define XSW(r, kf) ((r) * 128 + ((kf) ^ (4 * ((r) & 7))))

__device__ __forceinline__ void fma4(float* acc, float a, float4 b) {
    acc[0] += a * b.x; acc[1] += a * b.y; acc[2] += a * b.z; acc[3] += a * b.w;
}

// GEMM1: h1 = x @ W1 (50000x128 @ 128x128), grid (782, 2). Writes h1 as
// packed bf16x2 (gather payload); alphas computed from fp32 accumulators.
__global__ __launch_bounds__(256) void k_gemm1(
    const float* __restrict__ x, const float* __restrict__ W1,
    const float* __restrict__ a_s, const float* __restrict__ a_d,
    u32* __restrict__ h1b, float* __restrict__ as1, float* __restrict__ ad1)
{
    __shared__ float xs[64 * 128];   // 32 KB (swizzled)
    __shared__ float Wl[128 * 64];   // 32 KB
    const int tid = threadIdx.x;
    const int row0 = blockIdx.x * 64;
    const int j0 = blockIdx.y * 64;

    {   // stage W block: 128 k x 64 j
        const int f4c = tid & 15, kk = tid >> 4;
        for (int p = 0; p < 8; ++p) {
            const int k = kk + p * 16;
            *(float4*)(Wl + k * 64 + 4 * f4c) =
                *(const float4*)(W1 + k * IND + j0 + 4 * f4c);
        }
    }
    {   // stage x block: 64 rows x 128 k (swizzled)
        const int f4c = tid & 31, r = tid >> 5;
        for (int p = 0; p < 8; ++p) {
            const int rr = r + p * 8;
            const int row = row0 + rr;
            float4 v = make_float4(0.f, 0.f, 0.f, 0.f);
            if (row < NN) v = *(const float4*)(x + (size_t)row * IND + 4 * f4c);
            *(float4*)(xs + XSW(rr, 4 * f4c)) = v;
        }
    }
    __syncthreads();

    const int tc = tid & 15, tr = tid >> 4;
    float acc[4][4] = {};
    for (int k = 0; k < 128; k += 4) {
        const float4 B0 = *(const float4*)(Wl + (k + 0) * 64 + 4 * tc);
        const float4 B1 = *(const float4*)(Wl + (k + 1) * 64 + 4 * tc);
        const float4 B2 = *(const float4*)(Wl + (k + 2) * 64 + 4 * tc);
        const float4 B3 = *(const float4*)(Wl + (k + 3) * 64 + 4 * tc);
#pragma unroll
        for (int r = 0; r < 4; ++r) {
            const float4 A = *(const float4*)(xs + XSW(4 * tr + r, k));
            fma4(acc[r], A.x, B0); fma4(acc[r], A.y, B1);
            fma4(acc[r], A.z, B2); fma4(acc[r], A.w, B3);
        }
    }

    const float4 asv = *(const float4*)(a_s + j0 + 4 * tc);
    const float4 adv = *(const float4*)(a_d + j0 + 4 * tc);
#pragma unroll
    for (int r = 0; r < 4; ++r) {
        const int row = row0 + 4 * tr + r;
        if (row < NN) {   // guard uniform within shfl groups (varies by tr only)
            const u32 p01 = bf16rne(acc[r][0]) | (bf16rne(acc[r][1]) << 16);
            const u32 p23 = bf16rne(acc[r][2]) | (bf16rne(acc[r][3]) << 16);
            *(uint2*)(h1b + row * 64 + ((j0 + 4 * tc) >> 1)) = make_uint2(p01, p23);
            float ps = acc[r][0] * asv.x + acc[r][1] * asv.y +
                       acc[r][2] * asv.z + acc[r][3] * asv.w;
            float pd = acc[r][0] * adv.x + acc[r][1] * adv.y +
                       acc[r][2] * adv.z + acc[r][3] * adv.w;
            ps += __shfl_xor(ps, 1); ps += __shfl_xor(ps, 2);
            pd += __shfl_xor(pd, 1); pd += __shfl_xor(pd, 2);
            if ((tc & 3) == 0) {
                const int head = blockIdx.y * 4 + (tc >> 2);
                as1[row * NH + head] = ps;
                ad1[row * NH + head] = pd;
            }
        }
    }
}

// GEMM2: h2 = act2 @ W2 (50000x128 @ 128x64), grid (782, 1). Writes h2 as
// bf16 (ushort); fused single-head alpha2 epilogue from fp32 accumulators.
__global__ __launch_bounds__(256) void k_gemm2(
    const float* __restrict__ act2, const float* __restrict__ W2,
    const float* __restrict__ a_s2, const float* __restrict__ a_d2,
    u16* __restrict__ h2s, float* __restrict__ as2, float* __restrict__ ad2)
{
    __shared__ float xs[64 * 128];   // 32 KB (swizzled)
    __shared__ float Wl[128 * 64];   // 32 KB
    const int tid = threadIdx.x;
    const int row0 = blockIdx.x * 64;

    {
        const int f4c = tid & 15, kk = tid >> 4;
        for (int p = 0; p < 8; ++p) {
            const int k = kk + p * 16;
            *(float4*)(Wl + k * 64 + 4 * f4c) =
                *(const float4*)(W2 + k * OD + 4 * f4c);
        }
    }
    {
        const int f4c = tid & 31, r = tid >> 5;
        for (int p = 0; p < 8; ++p) {
            const int rr = r + p * 8;
            const int row = row0 + rr;
            float4 v = make_float4(0.f, 0.f, 0.f, 0.f);
            if (row < NN) v = *(const float4*)(act2 + (size_t)row * HIDD + 4 * f4c);
            *(float4*)(xs + XSW(rr, 4 * f4c)) = v;
        }
    }
    __syncthreads();

    const int tc = tid & 15, tr = tid >> 4;
    float acc[4][4] = {};
    for (int k = 0; k < 128; k += 4) {
        const float4 B0 = *(const float4*)(Wl + (k + 0) * 64 + 4 * tc);
        const float4 B1 = *(const float4*)(Wl + (k + 1) * 64 + 4 * tc);
        const float4 B2 = *(const float4*)(Wl + (k + 2) * 64 + 4 * tc);
        const float4 B3 = *(const float4*)(Wl + (k + 3) * 64 + 4 * tc);
#pragma unroll
        for (int r = 0; r < 4; ++r) {
            const float4 A = *(const float4*)(xs + XSW(4 * tr + r, k));
            fma4(acc[r], A.x, B0); fma4(acc[r], A.y, B1);
            fma4(acc[r], A.z, B2); fma4(acc[r], A.w, B3);
        }
    }

    const float4 asv = *(const float4*)(a_s2 + 4 * tc);
    const float4 adv = *(const float4*)(a_d2 + 4 * tc);
#pragma unroll
    for (int r = 0; r < 4; ++r) {
        const int row = row0 + 4 * tr + r;
        if (row < NN) {
            ushort4 pk;
            pk.x = (u16)bf16rne(acc[r][0]); pk.y = (u16)bf16rne(acc[r][1]);
            pk.z = (u16)bf16rne(acc[r][2]); pk.w = (u16)bf16rne(acc[r][3]);
            *(ushort4*)(h2s + row * 64 + 4 * tc) = pk;
            float ps = acc[r][0] * asv.x + acc[r][1] * asv.y +
                       acc[r][2] * asv.z + acc[r][3] * asv.w;
            float pd = acc[r][0] * adv.x + acc[r][1] * adv.y +
                       acc[r][2] * adv.z + acc[r][3] * adv.w;
            ps += __shfl_xor(ps, 1); ps += __shfl_xor(ps, 2);
            ps += __shfl_xor(ps, 4); ps += __shfl_xor(ps, 8);
            pd += __shfl_xor(pd, 1); pd += __shfl_xor(pd, 2);
            pd += __shfl_xor(pd, 4); pd += __shfl_xor(pd, 8);
            if (tc == 0) { as2[row] = ps; ad2[row] = pd; }
        }
    }
}

// ---------------------------------------------------------------------------
// Aggregation layer 1, CSR gather: one node per wave, lane covers channels
// 2*lane, 2*lane+1 via one packed-bf16 dword (head = lane>>3). Unroll-4.
// Per-edge exp is 8x-redundant across head lanes but VALU-cheap vs the
// LDS-pipe shuffle alternative (round-6 regression). Fuses /den + ELU.
// ---------------------------------------------------------------------------
__global__ __launch_bounds__(256) void k_agg1(
    const int* __restrict__ rowptr, const int* __restrict__ rowend,
    const u16* __restrict__ sorted16,
    const u32* __restrict__ h1b, const float* __restrict__ as1,
    const float* __restrict__ ad1,
    float* __restrict__ act2)
{
    const int node = blockIdx.x * 4 + (threadIdx.x >> 6);
    const int lane = threadIdx.x & 63;
    const int head = lane >> 3;
    const float adh = ad1[node * NH + head];
    const int k0 = rowptr[node], k1 = rowend[node];
    float acc0 = 0.f, acc1 = 0.f, den = 0.f;
    int k = k0;
    for (; k + 4 <= k1; k += 4) {
        const int s0 = sorted16[k],     s1 = sorted16[k + 1];
        const int s2 = sorted16[k + 2], s3 = sorted16[k + 3];
        const u32 u0 = h1b[s0 * 64 + lane];
        const u32 u1 = h1b[s1 * 64 + lane];
        const u32 u2 = h1b[s2 * 64 + lane];
        const u32 u3 = h1b[s3 * 64 + lane];
        const float a0 = as1[s0 * NH + head], a1 = as1[s1 * NH + head];
        const float a2 = as1[s2 * NH + head], a3 = as1[s3 * NH + head];
        const float w0 = __expf(LR(a0 + adh)), w1 = __expf(LR(a1 + adh));
        const float w2 = __expf(LR(a2 + adh)), w3 = __expf(LR(a3 + adh));
        acc0 += w0 * __uint_as_float(u0 << 16);
        acc1 += w0 * __uint_as_float(u0 & 0xffff0000u);
        acc0 += w1 * __uint_as_float(u1 << 16);
        acc1 += w1 * __uint_as_float(u1 & 0xffff0000u);
        acc0 += w2 * __uint_as_float(u2 << 16);
        acc1 += w2 * __uint_as_float(u2 & 0xffff0000u);
        acc0 += w3 * __uint_as_float(u3 << 16);
        acc1 += w3 * __uint_as_float(u3 & 0xffff0000u);
        den  += (w0 + w1) + (w2 + w3);
    }
    for (; k < k1; ++k) {
        const int src = sorted16[k];
        const float w = __expf(LR(as1[src * NH + head] + adh));
        const u32 u = h1b[src * 64 + lane];
        acc0 += w * __uint_as_float(u << 16);
        acc1 += w * __uint_as_float(u & 0xffff0000u);
        den += w;
    }
    const float inv = 1.f / den;                    // self-loop => den > 0
    float v0 = acc0 * inv, v1 = acc1 * inv;
    v0 = v0 > 0.f ? v0 : expm1f(v0);                // ELU
    v1 = v1 > 0.f ? v1 : expm1f(v1);
    *(float2*)(act2 + node * 128 + 2 * lane) = make_float2(v0, v1);
}

// ---------------------------------------------------------------------------
// Layer-2 edge weights, node-parallel (dst implicit = node): one wave per
// node, lanes stride the CSR row.
// ---------------------------------------------------------------------------
__global__ __launch_bounds__(256) void k_ew2n(
    const int* __restrict__ rowptr, const int* __restrict__ rowend,
    const u16* __restrict__ sorted16,
    const float* __restrict__ as2, const float* __restrict__ ad2,
    float* __restrict__ wbuf2)
{
    const int node = blockIdx.x * 4 + (threadIdx.x >> 6);
    const int lane = threadIdx.x & 63;
    const float adv = ad2[node];
    const int k1 = rowend[node];
    for (int k = rowptr[node] + lane; k < k1; k += 64)
        wbuf2[k] = __expf(LR(as2[(int)sorted16[k]] + adv));
}

// ---------------------------------------------------------------------------
// Aggregation layer 2 + log_softmax: one node per wave, lane = channel (64),
// bf16 h2 gather + precomputed weights (k wave-uniform -> scalar loads).
// Unroll-4. Fuses normalize + log_softmax -> output.
// ---------------------------------------------------------------------------
__global__ __launch_bounds__(256) void k_agg2(
    const int* __restrict__ rowptr, const int* __restrict__ rowend,
    const u16* __restrict__ sorted16, const float* __restrict__ wbuf2,
    const u16* __restrict__ h2s,
    float* __restrict__ out)
{
    const int node = blockIdx.x * 4 + (threadIdx.x >> 6);
    const int lane = threadIdx.x & 63;
    const int k0 = rowptr[node], k1 = rowend[node];
    float acc = 0.f, den = 0.f;
    int k = k0;
    for (; k + 4 <= k1; k += 4) {
        const int s0 = sorted16[k],     s1 = sorted16[k + 1];
        const int s2 = sorted16[k + 2], s3 = sorted16[k + 3];
        const float w0 = wbuf2[k],     w1 = wbuf2[k + 1];
        const float w2 = wbuf2[k + 2], w3 = wbuf2[k + 3];
        const u32 u0 = h2s[s0 * 64 + lane];
        const u32 u1 = h2s[s1 * 64 + lane];
        const u32 u2 = h2s[s2 * 64 + lane];
        const u32 u3 = h2s[s3 * 64 + lane];
        acc += w0 * __uint_as_float(u0 << 16);
        acc += w1 * __uint_as_float(u1 << 16);
        acc += w2 * __uint_as_float(u2 << 16);
        acc += w3 * __uint_as_float(u3 << 16);
        den += (w0 + w1) + (w2 + w3);
    }
    for (; k < k1; ++k) {
        const float w = wbuf2[k];
        acc += w * __uint_as_float((u32)h2s[(int)sorted16[k] * 64 + lane] << 16);
        den += w;
    }
    const float v = acc / den;
    float m = v;
    for (int kk = 1; kk < 64; kk <<= 1) m = fmaxf(m, __shfl_xor(m, kk));
    float se = __expf(v - m);
    for (int kk = 1; kk < 64; kk <<= 1) se += __shfl_xor(se, kk);
    out[node * 64 + lane] = v - m - logf(se);
}

// ---------------------------------------------------------------------------
// Workspace (~53.5 MB, 4-byte units):
//   h1b      [64N] u32 (bf16x2) -> after agg1, reused as h2s [64N] u16
//   as1      [8N]  f32 -> reused as as2 [N]
//   ad1      [8N]  f32 -> reused as ad2 [N]
//   act2     [128N] f32
//   rowptr   [N], rowend [N]
//   sorted16 [ET] u16 (= ET/2 u32 units)
//   wbuf2    [ET] f32
//   staging  [NPART*NB*CAPX] u32
//   cnt      [NPART*NB]
// ---------------------------------------------------------------------------
extern "C" void kernel_launch(void* const* d_in, const int* in_sizes, int n_in,
                              void* d_out, int out_size, void* d_ws, size_t ws_size,
                              hipStream_t stream)
{
    (void)in_sizes; (void)n_in; (void)out_size; (void)ws_size;
    const float* x    = (const float*)d_in[0];
    const int*   ei   = (const int*)d_in[1];
    const float* W1   = (const float*)d_in[2];
    const float* as1w = (const float*)d_in[3];
    const float* ad1w = (const float*)d_in[4];
    const float* W2   = (const float*)d_in[6];
    const float* as2w = (const float*)d_in[7];
    const float* ad2w = (const float*)d_in[8];
    float* out = (float*)d_out;

    float* ws = (float*)d_ws;
    u32*   h1b  = (u32*)ws;                           // 64N
    float* as1  = ws + (size_t)64 * NN;               // 8N
    float* ad1  = ws + (size_t)72 * NN;               // 8N
    float* act2 = ws + (size_t)80 * NN;               // 128N
    int*   rowptr = (int*)(ws + (size_t)208 * NN);    // N
    int*   rowend = rowptr + NN;                      // N
    u16*   sorted16 = (u16*)(rowend + NN);            // ET u16
    float* wbuf2 = (float*)((u32*)sorted16 + (ET + 1) / 2); // ET f32
    u32*   staging = (u32*)(wbuf2 + ET);              // NPART*NB*CAPX
    int*   cnt = (int*)(staging + (size_t)NPART * NB * CAPX); // NPART*NB
    u16*   h2s = (u16*)h1b;                           // alias (h1b dead after agg1)
    float* as2 = as1;
    float* ad2 = ad1;

    hipMemsetAsync(cnt, 0, NPART * NB * sizeof(int), stream);

    const int EB = (ET + 255) / 256;
    k_bin  <<<EB, 256, 0, stream>>>(ei, cnt, staging);
    k_place<<<NB, 1024, 0, stream>>>(cnt, staging, rowptr, rowend, sorted16);

    k_gemm1<<<dim3(782, 2), 256, 0, stream>>>(x, W1, as1w, ad1w, h1b, as1, ad1);
    k_agg1 <<<NN / 4, 256, 0, stream>>>(rowptr, rowend, sorted16, h1b, as1, ad1, act2);
    k_gemm2<<<dim3(782, 1), 256, 0, stream>>>(act2, W2, as2w, ad2w, h2s, as2, ad2);
    k_ew2n <<<NN / 4, 256, 0, stream>>>(rowptr, rowend, sorted16, as2, ad2, wbuf2);
    k_agg2 <<<NN / 4, 256, 0, stream>>>(rowptr, rowend, sorted16, wbuf2, h2s, out);
}

// Round 9
// 302.350 us; speedup vs baseline: 1.2459x; 1.2459x over previous
//
#include <hip/hip_runtime.h>
#include <math.h>

typedef unsigned int  u32;
typedef unsigned short u16;

// Problem constants (match reference)
#define NN    50000
#define NE    800000
#define ET    (NE + NN)     // edges + self loops = 850000
#define IND   128
#define HIDD  128
#define NH    8
#define OD    64
#define SLOPE 0.2f

// Binned counting sort parameters
#define NB    196           // buckets of 256 nodes: ceil(50000/256)
#define NPART 8             // XCD-aligned sub-buckets (blockIdx & 7)
#define CAPX  1024          // capacity per (part,bucket): mean 542, +20 sigma
#define CPAD  16            // counter stride in ints (64 B = own cache line)

// bf16 round-to-nearest-even, returns low 16 bits
__device__ __forceinline__ u32 bf16rne(float f) {
    u32 u = __float_as_uint(f);
    return (u + 0x7fffu + ((u >> 16) & 1u)) >> 16;
}

// leaky_relu(s) == max(s, SLOPE*s) for 0 < SLOPE < 1
#define LR(s) fmaxf((s), SLOPE * (s))

// ---------------------------------------------------------------------------
// Phase 1: bin edges by (part, dst>>8). Sequential writes per sub-bucket
// frontier; counters padded to one per 64B line (round-8 lesson: 1568
// counters packed in 98 lines serialized ~8700 atomics/line -> 128 us).
// ---------------------------------------------------------------------------
__global__ __launch_bounds__(256) void k_bin(
    const int* __restrict__ ei, int* __restrict__ cnt, u32* __restrict__ staging)
{
    const int e = blockIdx.x * 256 + threadIdx.x;
    if (e >= ET) return;
    int src, dst;
    if (e < NE) { src = ei[e]; dst = ei[NE + e]; }
    else        { src = dst = e - NE; }
    const int slot = (blockIdx.x & (NPART - 1)) * NB + (dst >> 8);
    const int pos = atomicAdd(&cnt[slot * CPAD], 1);
    staging[slot * CAPX + pos] = ((u32)(dst & 255) << 16) | (u32)src;
}

// ---------------------------------------------------------------------------
// Phase 2: one block per bucket (256 consecutive nodes = contiguous CSR
// region). LDS histogram -> scan -> emits rowptr/rowend -> places u16 src
// via LDS cursors. Random writes confined to ~9 KB owned by this CU.
// ---------------------------------------------------------------------------
__global__ __launch_bounds__(1024) void k_place(
    const int* __restrict__ cnt, const u32* __restrict__ staging,
    int* __restrict__ rowptr, int* __restrict__ rowend,
    u16* __restrict__ sorted16)
{
    __shared__ int tot[NB];
    __shared__ int scnt[NPART];
    __shared__ int hist[256];
    __shared__ int cur[256];
    __shared__ int scan[256];
    __shared__ int cbase;
    const int b = blockIdx.x;
    const int t = threadIdx.x;

    if (t < NB) {
        int s = 0;
        for (int p = 0; p < NPART; ++p) s += cnt[(p * NB + t) * CPAD];
        tot[t] = s;
    }
    if (t < NPART) scnt[t] = cnt[(t * NB + b) * CPAD];
    if (t < 256) hist[t] = 0;
    __syncthreads();
    if (t == 0) {                        // CSR base of this bucket
        int run = 0;
        for (int i = 0; i < b; ++i) run += tot[i];
        cbase = run;
    }
    __syncthreads();
    const int base = cbase;

    // pass 1: per-node histogram
    for (int idx = t; idx < NPART * CAPX; idx += 1024) {
        const int p = idx >> 10;         // CAPX == 1024
        const int i = idx & (CAPX - 1);
        if (i < scnt[p]) {
            const u32 v = staging[(p * NB + b) * CAPX + i];
            atomicAdd(&hist[v >> 16], 1);
        }
    }
    __syncthreads();
    // inclusive scan (Hillis-Steele) over 256
    if (t < 256) scan[t] = hist[t];
    __syncthreads();
    for (int off = 1; off < 256; off <<= 1) {
        int v = 0;
        if (t < 256 && t >= off) v = scan[t - off];
        __syncthreads();
        if (t < 256) scan[t] += v;
        __syncthreads();
    }
    if (t < 256) {
        const int excl = (t == 0) ? 0 : scan[t - 1];
        cur[t] = excl;
        const int node = b * 256 + t;
        if (node < NN) {
            rowptr[node] = base + excl;
            rowend[node] = base + excl + hist[t];
        }
    }
    __syncthreads();
    // pass 2: place (staged data is L2-hot from pass 1)
    for (int idx = t; idx < NPART * CAPX; idx += 1024) {
        const int p = idx >> 10;
        const int i = idx & (CAPX - 1);
        if (i < scnt[p]) {
            const u32 v = staging[(p * NB + b) * CAPX + i];
            const int pos = atomicAdd(&cur[v >> 16], 1);
            sorted16[base + pos] = (u16)(v & 0xffffu);
        }
    }
}

// ---------------------------------------------------------------------------
// Register-tiled fp32 GEMMs (64x64 C tile, K=128 staged, XOR-swizzled x tile).
// ---------------------------------------------------------------------------
#define XSW(r, kf) ((r) * 128 + ((kf) ^ (4 * ((r) & 7))))

__device__ __forceinline__ void fma4(float* acc, float a, float4 b) {
    acc[0] += a * b.x; acc[1] += a * b.y; acc[2] += a * b.z; acc[3] += a * b.w;
}

// GEMM1: h1 = x @ W1 (50000x128 @ 128x128), grid (782, 2). Writes h1 as
// packed bf16x2 (gather payload); alphas computed from fp32 accumulators.
__global__ __launch_bounds__(256) void k_gemm1(
    const float* __restrict__ x, const float* __restrict__ W1,
    const float* __restrict__ a_s, const float* __restrict__ a_d,
    u32* __restrict__ h1b, float* __restrict__ as1, float* __restrict__ ad1)
{
    __shared__ float xs[64 * 128];   // 32 KB (swizzled)
    __shared__ float Wl[128 * 64];   // 32 KB
    const int tid = threadIdx.x;
    const int row0 = blockIdx.x * 64;
    const int j0 = blockIdx.y * 64;

    {   // stage W block: 128 k x 64 j
        const int f4c = tid & 15, kk = tid >> 4;
        for (int p = 0; p < 8; ++p) {
            const int k = kk + p * 16;
            *(float4*)(Wl + k * 64 + 4 * f4c) =
                *(const float4*)(W1 + k * IND + j0 + 4 * f4c);
        }
    }
    {   // stage x block: 64 rows x 128 k (swizzled)
        const int f4c = tid & 31, r = tid >> 5;
        for (int p = 0; p < 8; ++p) {
            const int rr = r + p * 8;
            const int row = row0 + rr;
            float4 v = make_float4(0.f, 0.f, 0.f, 0.f);
            if (row < NN) v = *(const float4*)(x + (size_t)row * IND + 4 * f4c);
            *(float4*)(xs + XSW(rr, 4 * f4c)) = v;
        }
    }
    __syncthreads();

    const int tc = tid & 15, tr = tid >> 4;
    float acc[4][4] = {};
    for (int k = 0; k < 128; k += 4) {
        const float4 B0 = *(const float4*)(Wl + (k + 0) * 64 + 4 * tc);
        const float4 B1 = *(const float4*)(Wl + (k + 1) * 64 + 4 * tc);
        const float4 B2 = *(const float4*)(Wl + (k + 2) * 64 + 4 * tc);
        const float4 B3 = *(const float4*)(Wl + (k + 3) * 64 + 4 * tc);
#pragma unroll
        for (int r = 0; r < 4; ++r) {
            const float4 A = *(const float4*)(xs + XSW(4 * tr + r, k));
            fma4(acc[r], A.x, B0); fma4(acc[r], A.y, B1);
            fma4(acc[r], A.z, B2); fma4(acc[r], A.w, B3);
        }
    }

    const float4 asv = *(const float4*)(a_s + j0 + 4 * tc);
    const float4 adv = *(const float4*)(a_d + j0 + 4 * tc);
#pragma unroll
    for (int r = 0; r < 4; ++r) {
        const int row = row0 + 4 * tr + r;
        if (row < NN) {   // guard uniform within shfl groups (varies by tr only)
            const u32 p01 = bf16rne(acc[r][0]) | (bf16rne(acc[r][1]) << 16);
            const u32 p23 = bf16rne(acc[r][2]) | (bf16rne(acc[r][3]) << 16);
            *(uint2*)(h1b + row * 64 + ((j0 + 4 * tc) >> 1)) = make_uint2(p01, p23);
            float ps = acc[r][0] * asv.x + acc[r][1] * asv.y +
                       acc[r][2] * asv.z + acc[r][3] * asv.w;
            float pd = acc[r][0] * adv.x + acc[r][1] * adv.y +
                       acc[r][2] * adv.z + acc[r][3] * adv.w;
            ps += __shfl_xor(ps, 1); ps += __shfl_xor(ps, 2);
            pd += __shfl_xor(pd, 1); pd += __shfl_xor(pd, 2);
            if ((tc & 3) == 0) {
                const int head = blockIdx.y * 4 + (tc >> 2);
                as1[row * NH + head] = ps;
                ad1[row * NH + head] = pd;
            }
        }
    }
}

// GEMM2: h2 = act2 @ W2 (50000x128 @ 128x64), grid (782, 1). Writes h2 as
// bf16 (ushort); fused single-head alpha2 epilogue from fp32 accumulators.
__global__ __launch_bounds__(256) void k_gemm2(
    const float* __restrict__ act2, const float* __restrict__ W2,
    const float* __restrict__ a_s2, const float* __restrict__ a_d2,
    u16* __restrict__ h2s, float* __restrict__ as2, float* __restrict__ ad2)
{
    __shared__ float xs[64 * 128];   // 32 KB (swizzled)
    __shared__ float Wl[128 * 64];   // 32 KB
    const int tid = threadIdx.x;
    const int row0 = blockIdx.x * 64;

    {
        const int f4c = tid & 15, kk = tid >> 4;
        for (int p = 0; p < 8; ++p) {
            const int k = kk + p * 16;
            *(float4*)(Wl + k * 64 + 4 * f4c) =
                *(const float4*)(W2 + k * OD + 4 * f4c);
        }
    }
    {
        const int f4c = tid & 31, r = tid >> 5;
        for (int p = 0; p < 8; ++p) {
            const int rr = r + p * 8;
            const int row = row0 + rr;
            float4 v = make_float4(0.f, 0.f, 0.f, 0.f);
            if (row < NN) v = *(const float4*)(act2 + (size_t)row * HIDD + 4 * f4c);
            *(float4*)(xs + XSW(rr, 4 * f4c)) = v;
        }
    }
    __syncthreads();

    const int tc = tid & 15, tr = tid >> 4;
    float acc[4][4] = {};
    for (int k = 0; k < 128; k += 4) {
        const float4 B0 = *(const float4*)(Wl + (k + 0) * 64 + 4 * tc);
        const float4 B1 = *(const float4*)(Wl + (k + 1) * 64 + 4 * tc);
        const float4 B2 = *(const float4*)(Wl + (k + 2) * 64 + 4 * tc);
        const float4 B3 = *(const float4*)(Wl + (k + 3) * 64 + 4 * tc);
#pragma unroll
        for (int r = 0; r < 4; ++r) {
            const float4 A = *(const float4*)(xs + XSW(4 * tr + r, k));
            fma4(acc[r], A.x, B0); fma4(acc[r], A.y, B1);
            fma4(acc[r], A.z, B2); fma4(acc[r], A.w, B3);
        }
    }

    const float4 asv = *(const float4*)(a_s2 + 4 * tc);
    const float4 adv = *(const float4*)(a_d2 + 4 * tc);
#pragma unroll
    for (int r = 0; r < 4; ++r) {
        const int row = row0 + 4 * tr + r;
        if (row < NN) {
            ushort4 pk;
            pk.x = (u16)bf16rne(acc[r][0]); pk.y = (u16)bf16rne(acc[r][1]);
            pk.z = (u16)bf16rne(acc[r][2]); pk.w = (u16)bf16rne(acc[r][3]);
            *(ushort4*)(h2s + row * 64 + 4 * tc) = pk;
            float ps = acc[r][0] * asv.x + acc[r][1] * asv.y +
                       acc[r][2] * asv.z + acc[r][3] * asv.w;
            float pd = acc[r][0] * adv.x + acc[r][1] * adv.y +
                       acc[r][2] * adv.z + acc[r][3] * adv.w;
            ps += __shfl_xor(ps, 1); ps += __shfl_xor(ps, 2);
            ps += __shfl_xor(ps, 4); ps += __shfl_xor(ps, 8);
            pd += __shfl_xor(pd, 1); pd += __shfl_xor(pd, 2);
            pd += __shfl_xor(pd, 4); pd += __shfl_xor(pd, 8);
            if (tc == 0) { as2[row] = ps; ad2[row] = pd; }
        }
    }
}

// ---------------------------------------------------------------------------
// Aggregation layer 1, CSR gather: one node per wave, lane covers channels
// 2*lane, 2*lane+1 via one packed-bf16 dword (head = lane>>3). Unroll-4.
// Per-edge exp is 8x-redundant across head lanes but VALU-cheap vs the
// LDS-pipe shuffle alternative (round-6 regression). Fuses /den + ELU.
// ---------------------------------------------------------------------------
__global__ __launch_bounds__(256) void k_agg1(
    const int* __restrict__ rowptr, const int* __restrict__ rowend,
    const u16* __restrict__ sorted16,
    const u32* __restrict__ h1b, const float* __restrict__ as1,
    const float* __restrict__ ad1,
    float* __restrict__ act2)
{
    const int node = blockIdx.x * 4 + (threadIdx.x >> 6);
    const int lane = threadIdx.x & 63;
    const int head = lane >> 3;
    const float adh = ad1[node * NH + head];
    const int k0 = rowptr[node], k1 = rowend[node];
    float acc0 = 0.f, acc1 = 0.f, den = 0.f;
    int k = k0;
    for (; k + 4 <= k1; k += 4) {
        const int s0 = sorted16[k],     s1 = sorted16[k + 1];
        const int s2 = sorted16[k + 2], s3 = sorted16[k + 3];
        const u32 u0 = h1b[s0 * 64 + lane];
        const u32 u1 = h1b[s1 * 64 + lane];
        const u32 u2 = h1b[s2 * 64 + lane];
        const u32 u3 = h1b[s3 * 64 + lane];
        const float a0 = as1[s0 * NH + head], a1 = as1[s1 * NH + head];
        const float a2 = as1[s2 * NH + head], a3 = as1[s3 * NH + head];
        const float w0 = __expf(LR(a0 + adh)), w1 = __expf(LR(a1 + adh));
        const float w2 = __expf(LR(a2 + adh)), w3 = __expf(LR(a3 + adh));
        acc0 += w0 * __uint_as_float(u0 << 16);
        acc1 += w0 * __uint_as_float(u0 & 0xffff0000u);
        acc0 += w1 * __uint_as_float(u1 << 16);
        acc1 += w1 * __uint_as_float(u1 & 0xffff0000u);
        acc0 += w2 * __uint_as_float(u2 << 16);
        acc1 += w2 * __uint_as_float(u2 & 0xffff0000u);
        acc0 += w3 * __uint_as_float(u3 << 16);
        acc1 += w3 * __uint_as_float(u3 & 0xffff0000u);
        den  += (w0 + w1) + (w2 + w3);
    }
    for (; k < k1; ++k) {
        const int src = sorted16[k];
        const float w = __expf(LR(as1[src * NH + head] + adh));
        const u32 u = h1b[src * 64 + lane];
        acc0 += w * __uint_as_float(u << 16);
        acc1 += w * __uint_as_float(u & 0xffff0000u);
        den += w;
    }
    const float inv = 1.f / den;                    // self-loop => den > 0
    float v0 = acc0 * inv, v1 = acc1 * inv;
    v0 = v0 > 0.f ? v0 : expm1f(v0);                // ELU
    v1 = v1 > 0.f ? v1 : expm1f(v1);
    *(float2*)(act2 + node * 128 + 2 * lane) = make_float2(v0, v1);
}

// ---------------------------------------------------------------------------
// Layer-2 edge weights, node-parallel (dst implicit = node): one wave per
// node, lanes stride the CSR row.
// ---------------------------------------------------------------------------
__global__ __launch_bounds__(256) void k_ew2n(
    const int* __restrict__ rowptr, const int* __restrict__ rowend,
    const u16* __restrict__ sorted16,
    const float* __restrict__ as2, const float* __restrict__ ad2,
    float* __restrict__ wbuf2)
{
    const int node = blockIdx.x * 4 + (threadIdx.x >> 6);
    const int lane = threadIdx.x & 63;
    const float adv = ad2[node];
    const int k1 = rowend[node];
    for (int k = rowptr[node] + lane; k < k1; k += 64)
        wbuf2[k] = __expf(LR(as2[(int)sorted16[k]] + adv));
}

// ---------------------------------------------------------------------------
// Aggregation layer 2 + log_softmax: one node per wave, lane = channel (64),
// bf16 h2 gather + precomputed weights (k wave-uniform -> scalar loads).
// Unroll-4. Fuses normalize + log_softmax -> output.
// ---------------------------------------------------------------------------
__global__ __launch_bounds__(256) void k_agg2(
    const int* __restrict__ rowptr, const int* __restrict__ rowend,
    const u16* __restrict__ sorted16, const float* __restrict__ wbuf2,
    const u16* __restrict__ h2s,
    float* __restrict__ out)
{
    const int node = blockIdx.x * 4 + (threadIdx.x >> 6);
    const int lane = threadIdx.x & 63;
    const int k0 = rowptr[node], k1 = rowend[node];
    float acc = 0.f, den = 0.f;
    int k = k0;
    for (; k + 4 <= k1; k += 4) {
        const int s0 = sorted16[k],     s1 = sorted16[k + 1];
        const int s2 = sorted16[k + 2], s3 = sorted16[k + 3];
        const float w0 = wbuf2[k],     w1 = wbuf2[k + 1];
        const float w2 = wbuf2[k + 2], w3 = wbuf2[k + 3];
        const u32 u0 = h2s[s0 * 64 + lane];
        const u32 u1 = h2s[s1 * 64 + lane];
        const u32 u2 = h2s[s2 * 64 + lane];
        const u32 u3 = h2s[s3 * 64 + lane];
        acc += w0 * __uint_as_float(u0 << 16);
        acc += w1 * __uint_as_float(u1 << 16);
        acc += w2 * __uint_as_float(u2 << 16);
        acc += w3 * __uint_as_float(u3 << 16);
        den += (w0 + w1) + (w2 + w3);
    }
    for (; k < k1; ++k) {
        const float w = wbuf2[k];
        acc += w * __uint_as_float((u32)h2s[(int)sorted16[k] * 64 + lane] << 16);
        den += w;
    }
    const float v = acc / den;
    float m = v;
    for (int kk = 1; kk < 64; kk <<= 1) m = fmaxf(m, __shfl_xor(m, kk));
    float se = __expf(v - m);
    for (int kk = 1; kk < 64; kk <<= 1) se += __shfl_xor(se, kk);
    out[node * 64 + lane] = v - m - logf(se);
}

// ---------------------------------------------------------------------------
// Workspace (~53.6 MB, 4-byte units):
//   h1b      [64N] u32 (bf16x2) -> after agg1, reused as h2s [64N] u16
//   as1      [8N]  f32 -> reused as as2 [N]
//   ad1      [8N]  f32 -> reused as ad2 [N]
//   act2     [128N] f32
//   rowptr   [N], rowend [N]
//   sorted16 [ET] u16 (= ET/2 u32 units)
//   wbuf2    [ET] f32
//   staging  [NPART*NB*CAPX] u32
//   cnt      [NPART*NB*CPAD] (64B-padded counters)
// ---------------------------------------------------------------------------
extern "C" void kernel_launch(void* const* d_in, const int* in_sizes, int n_in,
                              void* d_out, int out_size, void* d_ws, size_t ws_size,
                              hipStream_t stream)
{
    (void)in_sizes; (void)n_in; (void)out_size; (void)ws_size;
    const float* x    = (const float*)d_in[0];
    const int*   ei   = (const int*)d_in[1];
    const float* W1   = (const float*)d_in[2];
    const float* as1w = (const float*)d_in[3];
    const float* ad1w = (const float*)d_in[4];
    const float* W2   = (const float*)d_in[6];
    const float* as2w = (const float*)d_in[7];
    const float* ad2w = (const float*)d_in[8];
    float* out = (float*)d_out;

    float* ws = (float*)d_ws;
    u32*   h1b  = (u32*)ws;                           // 64N
    float* as1  = ws + (size_t)64 * NN;               // 8N
    float* ad1  = ws + (size_t)72 * NN;               // 8N
    float* act2 = ws + (size_t)80 * NN;               // 128N
    int*   rowptr = (int*)(ws + (size_t)208 * NN);    // N
    int*   rowend = rowptr + NN;                      // N
    u16*   sorted16 = (u16*)(rowend + NN);            // ET u16
    float* wbuf2 = (float*)((u32*)sorted16 + (ET + 1) / 2); // ET f32
    u32*   staging = (u32*)(wbuf2 + ET);              // NPART*NB*CAPX
    int*   cnt = (int*)(staging + (size_t)NPART * NB * CAPX); // NPART*NB*CPAD
    u16*   h2s = (u16*)h1b;                           // alias (h1b dead after agg1)
    float* as2 = as1;
    float* ad2 = ad1;

    hipMemsetAsync(cnt, 0, NPART * NB * CPAD * sizeof(int), stream);

    const int EB = (ET + 255) / 256;
    k_bin  <<<EB, 256, 0, stream>>>(ei, cnt, staging);
    k_place<<<NB, 1024, 0, stream>>>(cnt, staging, rowptr, rowend, sorted16);

    k_gemm1<<<dim3(782, 2), 256, 0, stream>>>(x, W1, as1w, ad1w, h1b, as1, ad1);
    k_agg1 <<<NN / 4, 256, 0, stream>>>(rowptr, rowend, sorted16, h1b, as1, ad1, act2);
    k_gemm2<<<dim3(782, 1), 256, 0, stream>>>(act2, W2, as2w, ad2w, h2s, as2, ad2);
    k_ew2n <<<NN / 4, 256, 0, stream>>>(rowptr, rowend, sorted16, as2, ad2, wbuf2);
    k_agg2 <<<NN / 4, 256, 0, stream>>>(rowptr, rowend, sorted16, wbuf2, h2s, out);
}

// Round 11
// 281.400 us; speedup vs baseline: 1.3386x; 1.0745x over previous
//
#include <hip/hip_runtime.h>
#include <math.h>

typedef unsigned int  u32;
typedef unsigned short u16;

// Problem constants (match reference)
#define NN    50000
#define NE    800000
#define ET    (NE + NN)     // edges + self loops = 850000
#define IND   128
#define HIDD  128
#define NH    8
#define OD    64
#define SLOPE 0.2f

// Binned counting sort parameters. Self-loops are NOT staged (round-10
// lesson: sequential self-loop dst overflows per-block LDS buckets; they're
// deterministic, k_place inserts them directly).
#define NB    196           // buckets of 256 nodes: ceil(50000/256)
#define EPB   4096          // edges per binning block
#define NBB   ((NE + EPB - 1) / EPB)   // 196 binning blocks (random edges only)
#define LCAP  64            // LDS cap per (block,bucket): mean 21, +9.4 sigma
#define CAPB  5120          // global cap per bucket: mean 4082, +13 sigma
#define CPAD  16            // counter stride in ints (64 B = own cache line)

// bf16 round-to-nearest-even, returns low 16 bits
__device__ __forceinline__ u32 bf16rne(float f) {
    u32 u = __float_as_uint(f);
    return (u + 0x7fffu + ((u >> 16) & 1u)) >> 16;
}

// leaky_relu(s) == max(s, SLOPE*s) for 0 < SLOPE < 1
#define LR(s) fmaxf((s), SLOPE * (s))

// ---------------------------------------------------------------------------
// Phase 1: LDS-staged radix partition over the NE random edges only.
// Per-block LDS bins + ONE global atomicAdd per (block,bucket) + sequential
// per-thread flush (lines merge in L2; round-9 lesson: per-edge global
// atomics serialize ~100ns/line-op with 9x write amp).
// ---------------------------------------------------------------------------
__global__ __launch_bounds__(256) void k_bin(
    const int* __restrict__ ei, int* __restrict__ cnt, u32* __restrict__ staging)
{
    __shared__ u32 lbuf[NB * LCAP];   // 50176 B
    __shared__ int lcnt[NB];
    __shared__ int gbase[NB];
    const int t = threadIdx.x;
    const int e0 = blockIdx.x * EPB;

    for (int i = t; i < NB; i += 256) lcnt[i] = 0;
    __syncthreads();

    for (int i = t; i < EPB; i += 256) {
        const int e = e0 + i;
        if (e >= NE) break;
        const int src = ei[e];
        const int dst = ei[NE + e];
        const int b = dst >> 8;
        const int p = atomicAdd(&lcnt[b], 1);       // LDS atomic (cheap)
        lbuf[b * LCAP + p] = ((u32)(dst & 255) << 16) | (u32)src;
    }
    __syncthreads();

    for (int i = t; i < NB; i += 256)
        gbase[i] = atomicAdd(&cnt[i * CPAD], lcnt[i]);
    __syncthreads();

    // flush: thread = bucket; sequential stores -> lines merge in L2
    for (int b = t; b < NB; b += 256) {
        const int n = lcnt[b];
        const int gb = gbase[b];
        u32* dstp = staging + (size_t)b * CAPB + gb;
        const u32* srcp = lbuf + b * LCAP;
        for (int j = 0; j < n; ++j) dstp[j] = srcp[j];
    }
}

// ---------------------------------------------------------------------------
// Phase 2: one block per bucket (256 consecutive nodes = contiguous CSR
// region). LDS histogram (seeded with 1 per valid node = its self-loop) ->
// scan -> emits rowptr/rowend, writes the self-loop as first entry of each
// row, then places staged u16 src via LDS cursors.
// ---------------------------------------------------------------------------
__global__ __launch_bounds__(1024) void k_place(
    const int* __restrict__ cnt, const u32* __restrict__ staging,
    int* __restrict__ rowptr, int* __restrict__ rowend,
    u16* __restrict__ sorted16)
{
    __shared__ int hist[256];
    __shared__ int cur[256];
    __shared__ int scan[256];
    __shared__ int cbase;
    const int b = blockIdx.x;
    const int t = threadIdx.x;
    const int tot = cnt[b * CPAD];

    if (t == 0) {                        // CSR base of this bucket:
        int run = 0;                     // staged counts + 256 self-loops/bucket
        for (int i = 0; i < b; ++i) run += cnt[i * CPAD] + 256;
        cbase = run;                     // (every bucket before b is full: 256 valid nodes)
    }
    if (t < 256) hist[t] = ((b * 256 + t) < NN) ? 1 : 0;   // seed self-loop
    __syncthreads();
    const int base = cbase;

    // pass 1: per-node histogram of staged edges
    for (int i = t; i < tot; i += 1024)
        atomicAdd(&hist[staging[(size_t)b * CAPB + i] >> 16], 1);
    __syncthreads();
    // inclusive scan (Hillis-Steele) over 256
    if (t < 256) scan[t] = hist[t];
    __syncthreads();
    for (int off = 1; off < 256; off <<= 1) {
        int v = 0;
        if (t < 256 && t >= off) v = scan[t - off];
        __syncthreads();
        if (t < 256) scan[t] += v;
        __syncthreads();
    }
    if (t < 256) {
        const int excl = (t == 0) ? 0 : scan[t - 1];
        const int node = b * 256 + t;
        if (node < NN) {
            rowptr[node] = base + excl;
            rowend[node] = base + excl + hist[t];
            sorted16[base + excl] = (u16)node;   // self-loop first in row
            cur[t] = excl + 1;
        } else {
            cur[t] = excl;
        }
    }
    __syncthreads();
    // pass 2: place staged edges (L2-hot from pass 1)
    for (int i = t; i < tot; i += 1024) {
        const u32 v = staging[(size_t)b * CAPB + i];
        const int pos = atomicAdd(&cur[v >> 16], 1);
        sorted16[base + pos] = (u16)(v & 0xffffu);
    }
}

// ---------------------------------------------------------------------------
// Register-tiled fp32 GEMMs (64x64 C tile, K=128 staged, XOR-swizzled x tile).
// ---------------------------------------------------------------------------
#define XSW(r, kf) ((r) * 128 + ((kf) ^ (4 * ((r) & 7))))

__device__ __forceinline__ void fma4(float* acc, float a, float4 b) {
    acc[0] += a * b.x; acc[1] += a * b.y; acc[2] += a * b.z; acc[3] += a * b.w;
}

// GEMM1: h1 = x @ W1 (50000x128 @ 128x128), grid (782, 2). Writes h1 as
// packed bf16x2 (gather payload); alphas computed from fp32 accumulators.
__global__ __launch_bounds__(256) void k_gemm1(
    const float* __restrict__ x, const float* __restrict__ W1,
    const float* __restrict__ a_s, const float* __restrict__ a_d,
    u32* __restrict__ h1b, float* __restrict__ as1, float* __restrict__ ad1)
{
    __shared__ float xs[64 * 128];   // 32 KB (swizzled)
    __shared__ float Wl[128 * 64];   // 32 KB
    const int tid = threadIdx.x;
    const int row0 = blockIdx.x * 64;
    const int j0 = blockIdx.y * 64;

    {   // stage W block: 128 k x 64 j
        const int f4c = tid & 15, kk = tid >> 4;
        for (int p = 0; p < 8; ++p) {
            const int k = kk + p * 16;
            *(float4*)(Wl + k * 64 + 4 * f4c) =
                *(const float4*)(W1 + k * IND + j0 + 4 * f4c);
        }
    }
    {   // stage x block: 64 rows x 128 k (swizzled)
        const int f4c = tid & 31, r = tid >> 5;
        for (int p = 0; p < 8; ++p) {
            const int rr = r + p * 8;
            const int row = row0 + rr;
            float4 v = make_float4(0.f, 0.f, 0.f, 0.f);
            if (row < NN) v = *(const float4*)(x + (size_t)row * IND + 4 * f4c);
            *(float4*)(xs + XSW(rr, 4 * f4c)) = v;
        }
    }
    __syncthreads();

    const int tc = tid & 15, tr = tid >> 4;
    float acc[4][4] = {};
    for (int k = 0; k < 128; k += 4) {
        const float4 B0 = *(const float4*)(Wl + (k + 0) * 64 + 4 * tc);
        const float4 B1 = *(const float4*)(Wl + (k + 1) * 64 + 4 * tc);
        const float4 B2 = *(const float4*)(Wl + (k + 2) * 64 + 4 * tc);
        const float4 B3 = *(const float4*)(Wl + (k + 3) * 64 + 4 * tc);
#pragma unroll
        for (int r = 0; r < 4; ++r) {
            const float4 A = *(const float4*)(xs + XSW(4 * tr + r, k));
            fma4(acc[r], A.x, B0); fma4(acc[r], A.y, B1);
            fma4(acc[r], A.z, B2); fma4(acc[r], A.w, B3);
        }
    }

    const float4 asv = *(const float4*)(a_s + j0 + 4 * tc);
    const float4 adv = *(const float4*)(a_d + j0 + 4 * tc);
#pragma unroll
    for (int r = 0; r < 4; ++r) {
        const int row = row0 + 4 * tr + r;
        if (row < NN) {   // guard uniform within shfl groups (varies by tr only)
            const u32 p01 = bf16rne(acc[r][0]) | (bf16rne(acc[r][1]) << 16);
            const u32 p23 = bf16rne(acc[r][2]) | (bf16rne(acc[r][3]) << 16);
            *(uint2*)(h1b + row * 64 + ((j0 + 4 * tc) >> 1)) = make_uint2(p01, p23);
            float ps = acc[r][0] * asv.x + acc[r][1] * asv.y +
                       acc[r][2] * asv.z + acc[r][3] * asv.w;
            float pd = acc[r][0] * adv.x + acc[r][1] * adv.y +
                       acc[r][2] * adv.z + acc[r][3] * adv.w;
            ps += __shfl_xor(ps, 1); ps += __shfl_xor(ps, 2);
            pd += __shfl_xor(pd, 1); pd += __shfl_xor(pd, 2);
            if ((tc & 3) == 0) {
                const int head = blockIdx.y * 4 + (tc >> 2);
                as1[row * NH + head] = ps;
                ad1[row * NH + head] = pd;
            }
        }
    }
}

// GEMM2: h2 = act2 @ W2 (50000x128 @ 128x64), grid (782, 1). Writes h2 as
// bf16 (ushort); fused single-head alpha2 epilogue from fp32 accumulators.
__global__ __launch_bounds__(256) void k_gemm2(
    const float* __restrict__ act2, const float* __restrict__ W2,
    const float* __restrict__ a_s2, const float* __restrict__ a_d2,
    u16* __restrict__ h2s, float* __restrict__ as2, float* __restrict__ ad2)
{
    __shared__ float xs[64 * 128];   // 32 KB (swizzled)
    __shared__ float Wl[128 * 64];   // 32 KB
    const int tid = threadIdx.x;
    const int row0 = blockIdx.x * 64;

    {
        const int f4c = tid & 15, kk = tid >> 4;
        for (int p = 0; p < 8; ++p) {
            const int k = kk + p * 16;
            *(float4*)(Wl + k * 64 + 4 * f4c) =
                *(const float4*)(W2 + k * OD + 4 * f4c);
        }
    }
    {
        const int f4c = tid & 31, r = tid >> 5;
        for (int p = 0; p < 8; ++p) {
            const int rr = r + p * 8;
            const int row = row0 + rr;
            float4 v = make_float4(0.f, 0.f, 0.f, 0.f);
            if (row < NN) v = *(const float4*)(act2 + (size_t)row * HIDD + 4 * f4c);
            *(float4*)(xs + XSW(rr, 4 * f4c)) = v;
        }
    }
    __syncthreads();

    const int tc = tid & 15, tr = tid >> 4;
    float acc[4][4] = {};
    for (int k = 0; k < 128; k += 4) {
        const float4 B0 = *(const float4*)(Wl + (k + 0) * 64 + 4 * tc);
        const float4 B1 = *(const float4*)(Wl + (k + 1) * 64 + 4 * tc);
        const float4 B2 = *(const float4*)(Wl + (k + 2) * 64 + 4 * tc);
        const float4 B3 = *(const float4*)(Wl + (k + 3) * 64 + 4 * tc);
#pragma unroll
        for (int r = 0; r < 4; ++r) {
            const float4 A = *(const float4*)(xs + XSW(4 * tr + r, k));
            fma4(acc[r], A.x, B0); fma4(acc[r], A.y, B1);
            fma4(acc[r], A.z, B2); fma4(acc[r], A.w, B3);
        }
    }

    const float4 asv = *(const float4*)(a_s2 + 4 * tc);
    const float4 adv = *(const float4*)(a_d2 + 4 * tc);
#pragma unroll
    for (int r = 0; r < 4; ++r) {
        const int row = row0 + 4 * tr + r;
        if (row < NN) {
            ushort4 pk;
            pk.x = (u16)bf16rne(acc[r][0]); pk.y = (u16)bf16rne(acc[r][1]);
            pk.z = (u16)bf16rne(acc[r][2]); pk.w = (u16)bf16rne(acc[r][3]);
            *(ushort4*)(h2s + row * 64 + 4 * tc) = pk;
            float ps = acc[r][0] * asv.x + acc[r][1] * asv.y +
                       acc[r][2] * asv.z + acc[r][3] * asv.w;
            float pd = acc[r][0] * adv.x + acc[r][1] * adv.y +
                       acc[r][2] * adv.z + acc[r][3] * adv.w;
            ps += __shfl_xor(ps, 1); ps += __shfl_xor(ps, 2);
            ps += __shfl_xor(ps, 4); ps += __shfl_xor(ps, 8);
            pd += __shfl_xor(pd, 1); pd += __shfl_xor(pd, 2);
            pd += __shfl_xor(pd, 4); pd += __shfl_xor(pd, 8);
            if (tc == 0) { as2[row] = ps; ad2[row] = pd; }
        }
    }
}

// ---------------------------------------------------------------------------
// Aggregation layer 1, CSR gather: one node per wave, lane covers channels
// 2*lane, 2*lane+1 via one packed-bf16 dword (head = lane>>3). Unroll-4.
// Per-edge exp is 8x-redundant across head lanes but VALU-cheap vs the
// LDS-pipe shuffle alternative (round-6 regression). Fuses /den + ELU.
// ---------------------------------------------------------------------------
__global__ __launch_bounds__(256) void k_agg1(
    const int* __restrict__ rowptr, const int* __restrict__ rowend,
    const u16* __restrict__ sorted16,
    const u32* __restrict__ h1b, const float* __restrict__ as1,
    const float* __restrict__ ad1,
    float* __restrict__ act2)
{
    const int node = blockIdx.x * 4 + (threadIdx.x >> 6);
    const int lane = threadIdx.x & 63;
    const int head = lane >> 3;
    const float adh = ad1[node * NH + head];
    const int k0 = rowptr[node], k1 = rowend[node];
    float acc0 = 0.f, acc1 = 0.f, den = 0.f;
    int k = k0;
    for (; k + 4 <= k1; k += 4) {
        const int s0 = sorted16[k],     s1 = sorted16[k + 1];
        const int s2 = sorted16[k + 2], s3 = sorted16[k + 3];
        const u32 u0 = h1b[s0 * 64 + lane];
        const u32 u1 = h1b[s1 * 64 + lane];
        const u32 u2 = h1b[s2 * 64 + lane];
        const u32 u3 = h1b[s3 * 64 + lane];
        const float a0 = as1[s0 * NH + head], a1 = as1[s1 * NH + head];
        const float a2 = as1[s2 * NH + head], a3 = as1[s3 * NH + head];
        const float w0 = __expf(LR(a0 + adh)), w1 = __expf(LR(a1 + adh));
        const float w2 = __expf(LR(a2 + adh)), w3 = __expf(LR(a3 + adh));
        acc0 += w0 * __uint_as_float(u0 << 16);
        acc1 += w0 * __uint_as_float(u0 & 0xffff0000u);
        acc0 += w1 * __uint_as_float(u1 << 16);
        acc1 += w1 * __uint_as_float(u1 & 0xffff0000u);
        acc0 += w2 * __uint_as_float(u2 << 16);
        acc1 += w2 * __uint_as_float(u2 & 0xffff0000u);
        acc0 += w3 * __uint_as_float(u3 << 16);
        acc1 += w3 * __uint_as_float(u3 & 0xffff0000u);
        den  += (w0 + w1) + (w2 + w3);
    }
    for (; k < k1; ++k) {
        const int src = sorted16[k];
        const float w = __expf(LR(as1[src * NH + head] + adh));
        const u32 u = h1b[src * 64 + lane];
        acc0 += w * __uint_as_float(u << 16);
        acc1 += w * __uint_as_float(u & 0xffff0000u);
        den += w;
    }
    const float inv = 1.f / den;                    // self-loop => den > 0
    float v0 = acc0 * inv, v1 = acc1 * inv;
    v0 = v0 > 0.f ? v0 : expm1f(v0);                // ELU
    v1 = v1 > 0.f ? v1 : expm1f(v1);
    *(float2*)(act2 + node * 128 + 2 * lane) = make_float2(v0, v1);
}

// ---------------------------------------------------------------------------
// Layer-2 edge weights, node-parallel (dst implicit = node): one wave per
// node, lanes stride the CSR row.
// ---------------------------------------------------------------------------
__global__ __launch_bounds__(256) void k_ew2n(
    const int* __restrict__ rowptr, const int* __restrict__ rowend,
    const u16* __restrict__ sorted16,
    const float* __restrict__ as2, const float* __restrict__ ad2,
    float* __restrict__ wbuf2)
{
    const int node = blockIdx.x * 4 + (threadIdx.x >> 6);
    const int lane = threadIdx.x & 63;
    const float adv = ad2[node];
    const int k1 = rowend[node];
    for (int k = rowptr[node] + lane; k < k1; k += 64)
        wbuf2[k] = __expf(LR(as2[(int)sorted16[k]] + adv));
}

// ---------------------------------------------------------------------------
// Aggregation layer 2 + log_softmax: one node per wave, lane = channel (64),
// bf16 h2 gather + precomputed weights (k wave-uniform -> scalar loads).
// Unroll-4. Fuses normalize + log_softmax -> output.
// ---------------------------------------------------------------------------
__global__ __launch_bounds__(256) void k_agg2(
    const int* __restrict__ rowptr, const int* __restrict__ rowend,
    const u16* __restrict__ sorted16, const float* __restrict__ wbuf2,
    const u16* __restrict__ h2s,
    float* __restrict__ out)
{
    const int node = blockIdx.x * 4 + (threadIdx.x >> 6);
    const int lane = threadIdx.x & 63;
    const int k0 = rowptr[node], k1 = rowend[node];
    float acc = 0.f, den = 0.f;
    int k = k0;
    for (; k + 4 <= k1; k += 4) {
        const int s0 = sorted16[k],     s1 = sorted16[k + 1];
        const int s2 = sorted16[k + 2], s3 = sorted16[k + 3];
        const float w0 = wbuf2[k],     w1 = wbuf2[k + 1];
        const float w2 = wbuf2[k + 2], w3 = wbuf2[k + 3];
        const u32 u0 = h2s[s0 * 64 + lane];
        const u32 u1 = h2s[s1 * 64 + lane];
        const u32 u2 = h2s[s2 * 64 + lane];
        const u32 u3 = h2s[s3 * 64 + lane];
        acc += w0 * __uint_as_float(u0 << 16);
        acc += w1 * __uint_as_float(u1 << 16);
        acc += w2 * __uint_as_float(u2 << 16);
        acc += w3 * __uint_as_float(u3 << 16);
        den += (w0 + w1) + (w2 + w3);
    }
    for (; k < k1; ++k) {
        const float w = wbuf2[k];
        acc += w * __uint_as_float((u32)h2s[(int)sorted16[k] * 64 + lane] << 16);
        den += w;
    }
    const float v = acc / den;
    float m = v;
    for (int kk = 1; kk < 64; kk <<= 1) m = fmaxf(m, __shfl_xor(m, kk));
    float se = __expf(v - m);
    for (int kk = 1; kk < 64; kk <<= 1) se += __shfl_xor(se, kk);
    out[node * 64 + lane] = v - m - logf(se);
}

// ---------------------------------------------------------------------------
// Workspace (~51 MB, 4-byte units):
//   h1b      [64N] u32 (bf16x2) -> after agg1, reused as h2s [64N] u16
//   as1      [8N]  f32 -> reused as as2 [N]
//   ad1      [8N]  f32 -> reused as ad2 [N]
//   act2     [128N] f32
//   rowptr   [N], rowend [N]
//   sorted16 [ET] u16 (= ET/2 u32 units)
//   wbuf2    [ET] f32
//   staging  [NB*CAPB] u32 (4 MB, random edges only)
//   cnt      [NB*CPAD] (64B-padded counters)
// ---------------------------------------------------------------------------
extern "C" void kernel_launch(void* const* d_in, const int* in_sizes, int n_in,
                              void* d_out, int out_size, void* d_ws, size_t ws_size,
                              hipStream_t stream)
{
    (void)in_sizes; (void)n_in; (void)out_size; (void)ws_size;
    const float* x    = (const float*)d_in[0];
    const int*   ei   = (const int*)d_in[1];
    const float* W1   = (const float*)d_in[2];
    const float* as1w = (const float*)d_in[3];
    const float* ad1w = (const float*)d_in[4];
    const float* W2   = (const float*)d_in[6];
    const float* as2w = (const float*)d_in[7];
    const float* ad2w = (const float*)d_in[8];
    float* out = (float*)d_out;

    float* ws = (float*)d_ws;
    u32*   h1b  = (u32*)ws;                           // 64N
    float* as1  = ws + (size_t)64 * NN;               // 8N
    float* ad1  = ws + (size_t)72 * NN;               // 8N
    float* act2 = ws + (size_t)80 * NN;               // 128N
    int*   rowptr = (int*)(ws + (size_t)208 * NN);    // N
    int*   rowend = rowptr + NN;                      // N
    u16*   sorted16 = (u16*)(rowend + NN);            // ET u16
    float* wbuf2 = (float*)((u32*)sorted16 + (ET + 1) / 2); // ET f32
    u32*   staging = (u32*)(wbuf2 + ET);              // NB*CAPB
    int*   cnt = (int*)(staging + (size_t)NB * CAPB); // NB*CPAD
    u16*   h2s = (u16*)h1b;                           // alias (h1b dead after agg1)
    float* as2 = as1;
    float* ad2 = ad1;

    hipMemsetAsync(cnt, 0, NB * CPAD * sizeof(int), stream);

    k_bin  <<<NBB, 256, 0, stream>>>(ei, cnt, staging);
    k_place<<<NB, 1024, 0, stream>>>(cnt, staging, rowptr, rowend, sorted16);

    k_gemm1<<<dim3(782, 2), 256, 0, stream>>>(x, W1, as1w, ad1w, h1b, as1, ad1);
    k_agg1 <<<NN / 4, 256, 0, stream>>>(rowptr, rowend, sorted16, h1b, as1, ad1, act2);
    k_gemm2<<<dim3(782, 1), 256, 0, stream>>>(act2, W2, as2w, ad2w, h2s, as2, ad2);
    k_ew2n <<<NN / 4, 256, 0, stream>>>(rowptr, rowend, sorted16, as2, ad2, wbuf2);
    k_agg2 <<<NN / 4, 256, 0, stream>>>(rowptr, rowend, sorted16, wbuf2, h2s, out);
}

// Round 12
// 256.983 us; speedup vs baseline: 1.4658x; 1.0950x over previous
//
#include <hip/hip_runtime.h>
#include <math.h>

typedef unsigned int  u32;
typedef unsigned short u16;
typedef short bf16x8 __attribute__((ext_vector_type(8)));   // 8 bf16 = 4 VGPRs
typedef float f32x4  __attribute__((ext_vector_type(4)));

// Problem constants (match reference)
#define NN    50000
#define NE    800000
#define ET    (NE + NN)     // edges + self loops = 850000
#define IND   128
#define HIDD  128
#define NH    8
#define OD    64
#define SLOPE 0.2f

// Binned counting sort parameters. Self-loops are NOT staged (round-10
// lesson: sequential self-loop dst overflows per-block LDS buckets; they're
// deterministic, k_place inserts them directly).
#define NB    196           // buckets of 256 nodes: ceil(50000/256)
#define EPB   4096          // edges per binning block
#define NBB   ((NE + EPB - 1) / EPB)   // 196 binning blocks (random edges only)
#define LCAP  64            // LDS cap per (block,bucket): mean 21, +9.4 sigma
#define CAPB  5120          // global cap per bucket: mean 4082, +13 sigma
#define CPAD  16            // counter stride in ints (64 B = own cache line)

// bf16 round-to-nearest-even, returns low 16 bits
__device__ __forceinline__ u32 bf16rne(float f) {
    u32 u = __float_as_uint(f);
    return (u + 0x7fffu + ((u >> 16) & 1u)) >> 16;
}

// leaky_relu(s) == max(s, SLOPE*s) for 0 < SLOPE < 1
#define LR(s) fmaxf((s), SLOPE * (s))

// ---------------------------------------------------------------------------
// Phase 1: LDS-staged radix partition over the NE random edges only.
// ---------------------------------------------------------------------------
__global__ __launch_bounds__(256) void k_bin(
    const int* __restrict__ ei, int* __restrict__ cnt, u32* __restrict__ staging)
{
    __shared__ u32 lbuf[NB * LCAP];   // 50176 B
    __shared__ int lcnt[NB];
    __shared__ int gbase[NB];
    const int t = threadIdx.x;
    const int e0 = blockIdx.x * EPB;

    for (int i = t; i < NB; i += 256) lcnt[i] = 0;
    __syncthreads();

    for (int i = t; i < EPB; i += 256) {
        const int e = e0 + i;
        if (e >= NE) break;
        const int src = ei[e];
        const int dst = ei[NE + e];
        const int b = dst >> 8;
        const int p = atomicAdd(&lcnt[b], 1);       // LDS atomic (cheap)
        lbuf[b * LCAP + p] = ((u32)(dst & 255) << 16) | (u32)src;
    }
    __syncthreads();

    for (int i = t; i < NB; i += 256)
        gbase[i] = atomicAdd(&cnt[i * CPAD], lcnt[i]);
    __syncthreads();

    // flush: thread = bucket; sequential stores -> lines merge in L2
    for (int b = t; b < NB; b += 256) {
        const int n = lcnt[b];
        const int gb = gbase[b];
        u32* dstp = staging + (size_t)b * CAPB + gb;
        const u32* srcp = lbuf + b * LCAP;
        for (int j = 0; j < n; ++j) dstp[j] = srcp[j];
    }
}

// ---------------------------------------------------------------------------
// Phase 2: one block per bucket. Histogram seeded with the self-loop,
// scan, emit rowptr/rowend + self-loop first, place staged u16 src.
// ---------------------------------------------------------------------------
__global__ __launch_bounds__(1024) void k_place(
    const int* __restrict__ cnt, const u32* __restrict__ staging,
    int* __restrict__ rowptr, int* __restrict__ rowend,
    u16* __restrict__ sorted16)
{
    __shared__ int hist[256];
    __shared__ int cur[256];
    __shared__ int scan[256];
    __shared__ int cbase;
    const int b = blockIdx.x;
    const int t = threadIdx.x;
    const int tot = cnt[b * CPAD];

    if (t == 0) {
        int run = 0;
        for (int i = 0; i < b; ++i) run += cnt[i * CPAD] + 256;
        cbase = run;
    }
    if (t < 256) hist[t] = ((b * 256 + t) < NN) ? 1 : 0;   // seed self-loop
    __syncthreads();
    const int base = cbase;

    for (int i = t; i < tot; i += 1024)
        atomicAdd(&hist[staging[(size_t)b * CAPB + i] >> 16], 1);
    __syncthreads();
    if (t < 256) scan[t] = hist[t];
    __syncthreads();
    for (int off = 1; off < 256; off <<= 1) {
        int v = 0;
        if (t < 256 && t >= off) v = scan[t - off];
        __syncthreads();
        if (t < 256) scan[t] += v;
        __syncthreads();
    }
    if (t < 256) {
        const int excl = (t == 0) ? 0 : scan[t - 1];
        const int node = b * 256 + t;
        if (node < NN) {
            rowptr[node] = base + excl;
            rowend[node] = base + excl + hist[t];
            sorted16[base + excl] = (u16)node;   // self-loop first in row
            cur[t] = excl + 1;
        } else {
            cur[t] = excl;
        }
    }
    __syncthreads();
    for (int i = t; i < tot; i += 1024) {
        const u32 v = staging[(size_t)b * CAPB + i];
        const int pos = atomicAdd(&cur[v >> 16], 1);
        sorted16[base + pos] = (u16)(v & 0xffffu);
    }
}

// ---------------------------------------------------------------------------
// Weight prep: transpose W1/W2 to bf16 Wt[j][k] (k contiguous) so MFMA
// B-fragments (8 consecutive k per lane) are 16B chunks. 24576 elems.
// ---------------------------------------------------------------------------
__global__ __launch_bounds__(256) void k_wprep(
    const float* __restrict__ W1, const float* __restrict__ W2,
    u16* __restrict__ Wt1, u16* __restrict__ Wt2)
{
    const int i = blockIdx.x * 256 + threadIdx.x;
    if (i < 128 * 128) {
        const int k = i >> 7, j = i & 127;
        Wt1[j * 128 + k] = (u16)bf16rne(W1[i]);
    } else {
        const int i2 = i - 128 * 128;        // W2: [128][64]
        const int k = i2 >> 6, j = i2 & 63;
        Wt2[j * 128 + k] = (u16)bf16rne(W2[i2]);
    }
}

// ---------------------------------------------------------------------------
// MFMA GEMM1: h1 = x @ W1 (50000x128 @ 128x128), bf16 inputs / fp32 acc.
// Block: 64 rows x 128 cols, 4 waves (wave w = rows 16w..16w+16, 8 col-tiles).
// LDS bf16 tiles with 16B-chunk XOR swizzle -> conflict-free ds_read_b128.
// Layouts (verified): A[m=lane&15][k=quad*8+j]; C/D col=lane&15,row=quad*4+r.
// Epilogue: u16 h1 stores + fused per-head alpha reductions.
// ---------------------------------------------------------------------------
__global__ __launch_bounds__(256) void k_gemm1(
    const float* __restrict__ x, const u16* __restrict__ Wt1,
    const float* __restrict__ a_s, const float* __restrict__ a_d,
    u16* __restrict__ h1s, float* __restrict__ as1, float* __restrict__ ad1)
{
    __shared__ u32 xb[64 * 64];    // 16 KB: 64 rows x 16 chunks x 16B (swizzled)
    __shared__ u32 Wb[128 * 64];   // 32 KB: 128 cols x 16 chunks x 16B (swizzled)
    const int tid = threadIdx.x;
    const int row0 = blockIdx.x * 64;

    {   // stage Wb from Wt1 (bf16 [j][k]): 2048 chunks
        const uint4* Wt = (const uint4*)Wt1;
        for (int p = 0; p < 8; ++p) {
            const int id = p * 256 + tid;
            const int n = id >> 4, c = id & 15;
            *(uint4*)(Wb + n * 64 + ((c ^ (n & 15)) << 2)) = Wt[n * 16 + c];
        }
    }
    // stage xb from x fp32 (convert to bf16): 1024 chunks
    for (int p = 0; p < 4; ++p) {
        const int id = p * 256 + tid;
        const int m = id >> 4, c = id & 15;
        const int row = row0 + m;
        uint4 v = make_uint4(0, 0, 0, 0);
        if (row < NN) {
            const float4 f0 = *(const float4*)(x + (size_t)row * 128 + c * 8);
            const float4 f1 = *(const float4*)(x + (size_t)row * 128 + c * 8 + 4);
            v.x = bf16rne(f0.x) | (bf16rne(f0.y) << 16);
            v.y = bf16rne(f0.z) | (bf16rne(f0.w) << 16);
            v.z = bf16rne(f1.x) | (bf16rne(f1.y) << 16);
            v.w = bf16rne(f1.z) | (bf16rne(f1.w) << 16);
        }
        *(uint4*)(xb + m * 64 + ((c ^ (m & 15)) << 2)) = v;
    }
    __syncthreads();

    const int w = tid >> 6, lane = tid & 63;
    const int nl = lane & 15, quad = lane >> 4;
    f32x4 acc[8] = {};
    for (int kk = 0; kk < 4; ++kk) {
        const int cm = kk * 4 + quad;
        const bf16x8 a = *(const bf16x8*)(xb + (16 * w + nl) * 64 + ((cm ^ nl) << 2));
#pragma unroll
        for (int tn = 0; tn < 8; ++tn) {
            const bf16x8 b = *(const bf16x8*)(Wb + (16 * tn + nl) * 64 + ((cm ^ nl) << 2));
            acc[tn] = __builtin_amdgcn_mfma_f32_16x16x32_bf16(a, b, acc[tn], 0, 0, 0);
        }
    }

#pragma unroll
    for (int tn = 0; tn < 8; ++tn) {
        const float aw = a_s[16 * tn + nl];
        const float dw = a_d[16 * tn + nl];
#pragma unroll
        for (int r = 0; r < 4; ++r) {
            const int row = row0 + 16 * w + quad * 4 + r;   // uniform in 16-lane group
            if (row < NN) {
                const float v = acc[tn][r];
                h1s[(size_t)row * 128 + 16 * tn + nl] = (u16)bf16rne(v);
                float ps = v * aw, pd = v * dw;
                ps += __shfl_xor(ps, 1); ps += __shfl_xor(ps, 2);
                ps += __shfl_xor(ps, 4); ps += __shfl_xor(ps, 8);
                pd += __shfl_xor(pd, 1); pd += __shfl_xor(pd, 2);
                pd += __shfl_xor(pd, 4); pd += __shfl_xor(pd, 8);
                if (nl == 0) {
                    as1[row * NH + tn] = ps;
                    ad1[row * NH + tn] = pd;
                }
            }
        }
    }
}

// ---------------------------------------------------------------------------
// MFMA GEMM2: h2 = act2 @ W2 (50000x128 @ 128x64). act2 already bf16-packed
// (written by k_agg1), staged with chunk swizzle; 4 col-tiles per wave.
// Epilogue: u16 h2 stores + fused single-head alpha reduction (cross-tile
// partials live in the same lane -> in-register sum, then 16-lane shfl).
// ---------------------------------------------------------------------------
__global__ __launch_bounds__(256) void k_gemm2(
    const u32* __restrict__ act2b, const u16* __restrict__ Wt2,
    const float* __restrict__ a_s2, const float* __restrict__ a_d2,
    u16* __restrict__ h2s, float* __restrict__ as2, float* __restrict__ ad2)
{
    __shared__ u32 xb[64 * 64];   // 16 KB
    __shared__ u32 Wb[64 * 64];   // 16 KB
    const int tid = threadIdx.x;
    const int row0 = blockIdx.x * 64;

    {   // stage Wb from Wt2 (bf16 [j<64][k<128]): 1024 chunks
        const uint4* Wt = (const uint4*)Wt2;
        for (int p = 0; p < 4; ++p) {
            const int id = p * 256 + tid;
            const int n = id >> 4, c = id & 15;
            *(uint4*)(Wb + n * 64 + ((c ^ (n & 15)) << 2)) = Wt[n * 16 + c];
        }
    }
    // stage xb from act2b (already bf16 row-major, 16 chunks/row)
    for (int p = 0; p < 4; ++p) {
        const int id = p * 256 + tid;
        const int m = id >> 4, c = id & 15;
        const int row = row0 + m;
        uint4 v = make_uint4(0, 0, 0, 0);
        if (row < NN) v = ((const uint4*)act2b)[(size_t)row * 16 + c];
        *(uint4*)(xb + m * 64 + ((c ^ (m & 15)) << 2)) = v;
    }
    __syncthreads();

    const int w = tid >> 6, lane = tid & 63;
    const int nl = lane & 15, quad = lane >> 4;
    f32x4 acc[4] = {};
    for (int kk = 0; kk < 4; ++kk) {
        const int cm = kk * 4 + quad;
        const bf16x8 a = *(const bf16x8*)(xb + (16 * w + nl) * 64 + ((cm ^ nl) << 2));
#pragma unroll
        for (int tn = 0; tn < 4; ++tn) {
            const bf16x8 b = *(const bf16x8*)(Wb + (16 * tn + nl) * 64 + ((cm ^ nl) << 2));
            acc[tn] = __builtin_amdgcn_mfma_f32_16x16x32_bf16(a, b, acc[tn], 0, 0, 0);
        }
    }

    float aw[4], dw[4];
#pragma unroll
    for (int tn = 0; tn < 4; ++tn) {
        aw[tn] = a_s2[16 * tn + nl];
        dw[tn] = a_d2[16 * tn + nl];
    }
#pragma unroll
    for (int r = 0; r < 4; ++r) {
        const int row = row0 + 16 * w + quad * 4 + r;   // uniform in 16-lane group
        if (row < NN) {
            float ps = 0.f, pd = 0.f;
#pragma unroll
            for (int tn = 0; tn < 4; ++tn) {
                const float v = acc[tn][r];
                h2s[(size_t)row * 64 + 16 * tn + nl] = (u16)bf16rne(v);
                ps += v * aw[tn];
                pd += v * dw[tn];
            }
            ps += __shfl_xor(ps, 1); ps += __shfl_xor(ps, 2);
            ps += __shfl_xor(ps, 4); ps += __shfl_xor(ps, 8);
            pd += __shfl_xor(pd, 1); pd += __shfl_xor(pd, 2);
            pd += __shfl_xor(pd, 4); pd += __shfl_xor(pd, 8);
            if (nl == 0) { as2[row] = ps; ad2[row] = pd; }
        }
    }
}

// ---------------------------------------------------------------------------
// Aggregation layer 1, CSR gather: one node per wave, lane = packed channel
// pair (head = lane>>3). Unroll-4. Fuses /den + ELU; writes act2 as bf16x2.
// ---------------------------------------------------------------------------
__global__ __launch_bounds__(256) void k_agg1(
    const int* __restrict__ rowptr, const int* __restrict__ rowend,
    const u16* __restrict__ sorted16,
    const u32* __restrict__ h1b, const float* __restrict__ as1,
    const float* __restrict__ ad1,
    u32* __restrict__ act2b)
{
    const int node = blockIdx.x * 4 + (threadIdx.x >> 6);
    const int lane = threadIdx.x & 63;
    const int head = lane >> 3;
    const float adh = ad1[node * NH + head];
    const int k0 = rowptr[node], k1 = rowend[node];
    float acc0 = 0.f, acc1 = 0.f, den = 0.f;
    int k = k0;
    for (; k + 4 <= k1; k += 4) {
        const int s0 = sorted16[k],     s1 = sorted16[k + 1];
        const int s2 = sorted16[k + 2], s3 = sorted16[k + 3];
        const u32 u0 = h1b[s0 * 64 + lane];
        const u32 u1 = h1b[s1 * 64 + lane];
        const u32 u2 = h1b[s2 * 64 + lane];
        const u32 u3 = h1b[s3 * 64 + lane];
        const float a0 = as1[s0 * NH + head], a1 = as1[s1 * NH + head];
        const float a2 = as1[s2 * NH + head], a3 = as1[s3 * NH + head];
        const float w0 = __expf(LR(a0 + adh)), w1 = __expf(LR(a1 + adh));
        const float w2 = __expf(LR(a2 + adh)), w3 = __expf(LR(a3 + adh));
        acc0 += w0 * __uint_as_float(u0 << 16);
        acc1 += w0 * __uint_as_float(u0 & 0xffff0000u);
        acc0 += w1 * __uint_as_float(u1 << 16);
        acc1 += w1 * __uint_as_float(u1 & 0xffff0000u);
        acc0 += w2 * __uint_as_float(u2 << 16);
        acc1 += w2 * __uint_as_float(u2 & 0xffff0000u);
        acc0 += w3 * __uint_as_float(u3 << 16);
        acc1 += w3 * __uint_as_float(u3 & 0xffff0000u);
        den  += (w0 + w1) + (w2 + w3);
    }
    for (; k < k1; ++k) {
        const int src = sorted16[k];
        const float w = __expf(LR(as1[src * NH + head] + adh));
        const u32 u = h1b[src * 64 + lane];
        acc0 += w * __uint_as_float(u << 16);
        acc1 += w * __uint_as_float(u & 0xffff0000u);
        den += w;
    }
    const float inv = 1.f / den;                    // self-loop => den > 0
    float v0 = acc0 * inv, v1 = acc1 * inv;
    v0 = v0 > 0.f ? v0 : expm1f(v0);                // ELU
    v1 = v1 > 0.f ? v1 : expm1f(v1);
    act2b[node * 64 + lane] = bf16rne(v0) | (bf16rne(v1) << 16);
}

// ---------------------------------------------------------------------------
// Layer-2 edge weights, node-parallel (dst implicit = node).
// ---------------------------------------------------------------------------
__global__ __launch_bounds__(256) void k_ew2n(
    const int* __restrict__ rowptr, const int* __restrict__ rowend,
    const u16* __restrict__ sorted16,
    const float* __restrict__ as2, const float* __restrict__ ad2,
    float* __restrict__ wbuf2)
{
    const int node = blockIdx.x * 4 + (threadIdx.x >> 6);
    const int lane = threadIdx.x & 63;
    const float adv = ad2[node];
    const int k1 = rowend[node];
    for (int k = rowptr[node] + lane; k < k1; k += 64)
        wbuf2[k] = __expf(LR(as2[(int)sorted16[k]] + adv));
}

// ---------------------------------------------------------------------------
// Aggregation layer 2 + log_softmax: one node per wave, lane = channel (64).
// ---------------------------------------------------------------------------
__global__ __launch_bounds__(256) void k_agg2(
    const int* __restrict__ rowptr, const int* __restrict__ rowend,
    const u16* __restrict__ sorted16, const float* __restrict__ wbuf2,
    const u16* __restrict__ h2s,
    float* __restrict__ out)
{
    const int node = blockIdx.x * 4 + (threadIdx.x >> 6);
    const int lane = threadIdx.x & 63;
    const int k0 = rowptr[node], k1 = rowend[node];
    float acc = 0.f, den = 0.f;
    int k = k0;
    for (; k + 4 <= k1; k += 4) {
        const int s0 = sorted16[k],     s1 = sorted16[k + 1];
        const int s2 = sorted16[k + 2], s3 = sorted16[k + 3];
        const float w0 = wbuf2[k],     w1 = wbuf2[k + 1];
        const float w2 = wbuf2[k + 2], w3 = wbuf2[k + 3];
        const u32 u0 = h2s[s0 * 64 + lane];
        const u32 u1 = h2s[s1 * 64 + lane];
        const u32 u2 = h2s[s2 * 64 + lane];
        const u32 u3 = h2s[s3 * 64 + lane];
        acc += w0 * __uint_as_float(u0 << 16);
        acc += w1 * __uint_as_float(u1 << 16);
        acc += w2 * __uint_as_float(u2 << 16);
        acc += w3 * __uint_as_float(u3 << 16);
        den += (w0 + w1) + (w2 + w3);
    }
    for (; k < k1; ++k) {
        const float w = wbuf2[k];
        acc += w * __uint_as_float((u32)h2s[(int)sorted16[k] * 64 + lane] << 16);
        den += w;
    }
    const float v = acc / den;
    float m = v;
    for (int kk = 1; kk < 64; kk <<= 1) m = fmaxf(m, __shfl_xor(m, kk));
    float se = __expf(v - m);
    for (int kk = 1; kk < 64; kk <<= 1) se += __shfl_xor(se, kk);
    out[node * 64 + lane] = v - m - logf(se);
}

// ---------------------------------------------------------------------------
// Workspace (4-byte units):
//   h1b      [64N] u32 (h1 bf16 row-major) -> reused as h2s [64N] u16
//   as1      [8N]  f32 -> reused as as2 [N]
//   ad1      [8N]  f32 -> reused as ad2 [N]
//   act2b    [64N] u32 (bf16x2 packed)
//   rowptr   [N], rowend [N]
//   sorted16 [ET] u16
//   wbuf2    [ET] f32
//   staging  [NB*CAPB] u32
//   cnt      [NB*CPAD]
//   Wt1      [8192] u32 (bf16 128x128), Wt2 [4096] u32 (bf16 64x128)
// ---------------------------------------------------------------------------
extern "C" void kernel_launch(void* const* d_in, const int* in_sizes, int n_in,
                              void* d_out, int out_size, void* d_ws, size_t ws_size,
                              hipStream_t stream)
{
    (void)in_sizes; (void)n_in; (void)out_size; (void)ws_size;
    const float* x    = (const float*)d_in[0];
    const int*   ei   = (const int*)d_in[1];
    const float* W1   = (const float*)d_in[2];
    const float* as1w = (const float*)d_in[3];
    const float* ad1w = (const float*)d_in[4];
    const float* W2   = (const float*)d_in[6];
    const float* as2w = (const float*)d_in[7];
    const float* ad2w = (const float*)d_in[8];
    float* out = (float*)d_out;

    float* ws = (float*)d_ws;
    u32*   h1b  = (u32*)ws;                           // 64N
    float* as1  = ws + (size_t)64 * NN;               // 8N
    float* ad1  = ws + (size_t)72 * NN;               // 8N
    u32*   act2b = (u32*)(ws + (size_t)80 * NN);      // 64N
    int*   rowptr = (int*)(ws + (size_t)144 * NN);    // N
    int*   rowend = rowptr + NN;                      // N
    u16*   sorted16 = (u16*)(rowend + NN);            // ET u16
    float* wbuf2 = (float*)((u32*)sorted16 + (ET + 1) / 2); // ET f32
    u32*   staging = (u32*)(wbuf2 + ET);              // NB*CAPB
    int*   cnt = (int*)(staging + (size_t)NB * CAPB); // NB*CPAD
    u16*   Wt1 = (u16*)(cnt + NB * CPAD);             // 8192 u32
    u16*   Wt2 = Wt1 + 128 * 128;                     // 4096 u32
    u16*   h1s = (u16*)h1b;
    u16*   h2s = (u16*)h1b;                           // alias (h1 dead after agg1)
    float* as2 = as1;
    float* ad2 = ad1;

    hipMemsetAsync(cnt, 0, NB * CPAD * sizeof(int), stream);

    k_wprep<<<96, 256, 0, stream>>>(W1, W2, Wt1, Wt2);
    k_bin  <<<NBB, 256, 0, stream>>>(ei, cnt, staging);
    k_place<<<NB, 1024, 0, stream>>>(cnt, staging, rowptr, rowend, sorted16);

    k_gemm1<<<782, 256, 0, stream>>>(x, Wt1, as1w, ad1w, h1s, as1, ad1);
    k_agg1 <<<NN / 4, 256, 0, stream>>>(rowptr, rowend, sorted16, h1b, as1, ad1, act2b);
    k_gemm2<<<782, 256, 0, stream>>>(act2b, Wt2, as2w, ad2w, h2s, as2, ad2);
    k_ew2n <<<NN / 4, 256, 0, stream>>>(rowptr, rowend, sorted16, as2, ad2, wbuf2);
    k_agg2 <<<NN / 4, 256, 0, stream>>>(rowptr, rowend, sorted16, wbuf2, h2s, out);
}